// Round 11
// baseline (119.336 us; speedup 1.0000x reference)
//
#include <hip/hip_runtime.h>
#include <stdint.h>

// rotate-left via v_alignbit_b32 (1 instruction)
__device__ __forceinline__ uint32_t rotl(uint32_t v, int r) {
  return __builtin_amdgcn_alignbit(v, v, (uint32_t)(32 - r));
}

// ---------------- Threefry-2x32, 20 rounds (host key derivation) ----------
__host__ inline void tf2x32(uint32_t k0, uint32_t k1, uint32_t x0, uint32_t x1,
                            uint32_t& o0, uint32_t& o1) {
  uint32_t k2 = k0 ^ k1 ^ 0x1BD11BDAu;
#define TFR(r) { x0 += x1; x1 = (x1 << (r)) | (x1 >> (32 - (r))); x1 ^= x0; }
  x0 += k0; x1 += k1;
  TFR(13) TFR(15) TFR(26) TFR(6)  x0 += k1; x1 += k2 + 1u;
  TFR(17) TFR(29) TFR(16) TFR(24) x0 += k2; x1 += k0 + 2u;
  TFR(13) TFR(15) TFR(26) TFR(6)  x0 += k0; x1 += k1 + 3u;
  TFR(17) TFR(29) TFR(16) TFR(24) x0 += k1; x1 += k2 + 4u;
  TFR(13) TFR(15) TFR(26) TFR(6)  x0 += k2; x1 += k0 + 5u;
#undef TFR
  o0 = x0; o1 = x1;
}

// 4-chain lockstep threefry at counters (0, jb + STRIDE*i); out = o0^o1
// (JAX partitionable random_bits). Key injections fused into following
// round's add (v_add3), round-1 add merged into init.
template <unsigned STRIDE>
__device__ __forceinline__ void tf4(uint32_t k0, uint32_t k1, uint32_t jb,
                                    uint32_t out[4]) {
  uint32_t k2 = k0 ^ k1 ^ 0x1BD11BDAu;
  uint32_t k21 = k2 + 1u, k02 = k0 + 2u, k13 = k1 + 3u, k24 = k2 + 4u,
           k05 = k0 + 5u;
  uint32_t a[4], b[4];
  uint32_t jk = jb + k1;
#pragma unroll
  for (int i = 0; i < 4; ++i) {
    b[i] = jk + STRIDE * (unsigned)i;
    a[i] = k0 + b[i];                   // round-1 "a += b" merged with a = k0
  }
#pragma unroll
  for (int i = 0; i < 4; ++i) b[i] = rotl(b[i], 13) ^ a[i];  // round-1 tail
#define RND4(r)                                                        \
  _Pragma("unroll") for (int i = 0; i < 4; ++i) {                      \
    a[i] += b[i];                                                      \
    b[i] = rotl(b[i], (r)) ^ a[i];                                     \
  }
#define RNDI4(r, ka, kbn)                                              \
  _Pragma("unroll") for (int i = 0; i < 4; ++i) {                      \
    b[i] += (kbn);                                                     \
    a[i] = a[i] + (ka) + b[i];  /* v_add3_u32 */                       \
    b[i] = rotl(b[i], (r)) ^ a[i];                                     \
  }
  RND4(15) RND4(26) RND4(6)
  RNDI4(17, k1, k21) RND4(29) RND4(16) RND4(24)
  RNDI4(13, k2, k02) RND4(15) RND4(26) RND4(6)
  RNDI4(17, k0, k13) RND4(29) RND4(16) RND4(24)
  RNDI4(13, k1, k24) RND4(15) RND4(26) RND4(6)
#undef RND4
#undef RNDI4
#pragma unroll
  for (int i = 0; i < 4; ++i) out[i] = (a[i] + k2) ^ (b[i] + k05);
}

// bits -> float in [0,1): (bits>>9)|0x3F800000 bitcast - 1.0 (JAX _uniform)
__device__ __forceinline__ float bits_to_f01(uint32_t b) {
  return __uint_as_float((b >> 9) | 0x3F800000u) - 1.0f;
}

// order-preserving float<->uint encode for min on floats
__device__ __forceinline__ unsigned encf(float f) {
  unsigned u = __float_as_uint(f);
  return (u & 0x80000000u) ? ~u : (u | 0x80000000u);
}
__device__ __forceinline__ float decf(unsigned u) {
  unsigned b = (u & 0x80000000u) ? (u & 0x7FFFFFFFu) : ~u;
  return __uint_as_float(b);
}

struct TP {
  const float* x;
  float* out;
  int* midx;
  uint32_t uk0, uk1, nk0, nk1;
  unsigned k;         // N = 25 << k
  unsigned N;
  unsigned tot;       // 680 * N
  unsigned lo_cnt;    // nonclass chunks below class region
  unsigned hi_start;  // first chunk after class region
  unsigned nc_base, nc_end;    // prefix range of nonclass chunks
  unsigned cls_lo;             // first class-involved chunk
  unsigned cls_base, cls_end;  // prefix range of class chunks
  unsigned slot_base, slot_cnt;  // per-block min slots of this tensor
};

#define PREPB 263u

// process one 1024-elem chunk starting at element s of tensor P (4/thread)
template <bool CLS>
__device__ __forceinline__ void process_chunk(
    const TP& P, unsigned s, unsigned tid, float clsmin, float sv, float lo) {
  unsigned i0 = s + tid * 4u;
  if (i0 >= P.tot) return;

  unsigned bc = __umulhi(i0 >> P.k, 0x51EB851Fu) >> 3;  // (i0/2^k)/25
  unsigned n0 = i0 - bc * P.N;       // 4 consecutive n, same (b,c)
  unsigned b = (bc * 772u) >> 16;    // exact for bc < 680
  unsigned c = bc - b * 85u;

  float4 va = *reinterpret_cast<const float4*>(P.x + i0);

  // ---- noise bits: 4 lockstep threefry chains ----
  unsigned jb = (b * P.N + n0) * 85u + c;  // noise array [B,N,C] flat index
  uint32_t nb[4];
  tf4<85u>(P.nk0, P.nk1, jb, nb);

  // ---- zlite, coefficient-major; 3-term central + linear tail ----
  float x4[4], L4[4], t4[4], p4[4], nz[4];
#pragma unroll
  for (int q = 0; q < 4; ++q) {
    float f = __uint_as_float((nb[q] >> 9) | 0x3F800000u) - 1.0f;
    x4[q] = fmaf(f, 2.0f, lo);   // stays in [lo, 1): fmax redundant
  }
#pragma unroll
  for (int q = 0; q < 4; ++q) L4[q] = __log2f(fmaf(-x4[q], x4[q], 1.0f));
#pragma unroll
  for (int q = 0; q < 4; ++q) t4[q] = fmaf(L4[q], -0.69314718f, -2.5f);
#pragma unroll
  for (int q = 0; q < 4; ++q) p4[q] = fmaf(-0.00417768164f, t4[q], 0.246640727f);
#pragma unroll
  for (int q = 0; q < 4; ++q) p4[q] = fmaf(p4[q], t4[q], 1.50140941f);
#pragma unroll
  for (int q = 0; q < 4; ++q) {
    float pt = fmaf(L4[q], -0.1113356f, 1.327237f);   // tail (w>=5)
    p4[q] = (L4[q] > -7.2134752f) ? p4[q] : pt;
    nz[q] = p4[q] * x4[q];
  }

  float vv[4] = {va.x, va.y, va.z, va.w};

  if (CLS) {
    // ---- class scatter-replace (batch 0, channels 5..84) ----
    if (b == 0u && c >= 5u) {
      unsigned kk = c - 5u;
      int4 ma = *reinterpret_cast<const int4*>(P.midx + n0);
      uint32_t ub[4];
      tf4<80u>(P.uk0, P.uk1, n0 * 80u + kk, ub);   // uniform array [N,80]
      int mm[4] = {ma.x, ma.y, ma.z, ma.w};
#pragma unroll
      for (int q = 0; q < 4; ++q) {
        if ((unsigned)mm[q] != kk) vv[q] = bits_to_f01(ub[q]) * clsmin;
      }
    }
  }

#pragma unroll
  for (int q = 0; q < 4; ++q) vv[q] = fmaf(nz[q], sv, vv[q]);
  *reinterpret_cast<float4*>(P.out + i0) = make_float4(vv[0], vv[1], vv[2], vv[3]);
}

// ---------------- single dispatch: [prep][nonclass chunks][class chunks] ---
// Prep blocks (0..262) never wait and are grid-front => always dispatched
// first => no deadlock. Class blocks are grid-tail: by the time they launch,
// prep is long finished; their validity-spin executes once. Sync is
// init-free: encoded minima are nonzero with top bit 0 (min of N(0,1) < 0);
// 0xAA poison / zeroed memory fails the validity test.
__global__ __launch_bounds__(256) void mono(
    TP p0, TP p1, TP p2, unsigned* __restrict__ slots,
    const float* __restrict__ valuep) {
  const unsigned bid = blockIdx.x, tid = threadIdx.x;

  if (bid < PREPB) {
    // ---------- prep: per-pixel argmax + per-block min ----------
    const float* x; int* midx; unsigned N; unsigned lb;
    if (bid < 200u)      { x = p0.x; midx = p0.midx; N = 25600u; lb = bid; }
    else if (bid < 250u) { x = p1.x; midx = p1.midx; N = 6400u;  lb = bid - 200u; }
    else                 { x = p2.x; midx = p2.midx; N = 1600u;  lb = bid - 250u; }
    unsigned p = lb * 128u + (tid >> 1);
    unsigned h = tid & 1u;           // half: channels 40h .. 40h+39
    float best = -INFINITY, mn = INFINITY;
    int bi = 0;
    if (p < N) {
      const float* pp = x + (5u + 40u * h) * N + p;
#pragma unroll 8
      for (int k = 0; k < 40; ++k) {
        float v = pp[(unsigned)k * N];
        if (v > best) { best = v; bi = (int)(40u * h) + k; }  // '>': first max
        mn = fminf(mn, v);
      }
    }
    float ob = __shfl_xor(best, 1, 64);
    int obi = __shfl_xor(bi, 1, 64);
    float omn = __shfl_xor(mn, 1, 64);
    float bE = (h == 0u) ? best : ob;  int iE = (h == 0u) ? bi : obi;
    float bO = (h == 0u) ? ob : best;  int iO = (h == 0u) ? obi : bi;
    int mbi = (bO > bE) ? iO : iE;     // ties -> lower-k half (first max)
    mn = fminf(mn, omn);
    if (h == 0u && p < N) midx[p] = mbi;
    unsigned u = encf(mn);
    for (int off = 32; off > 0; off >>= 1) {
      unsigned o = __shfl_down(u, (unsigned)off, 64);
      u = (o < u) ? o : u;
    }
    __shared__ unsigned lsp[4];
    if ((tid & 63u) == 0u) lsp[tid >> 6] = u;
    __syncthreads();   // also orders this block's midx stores before release
    if (tid == 0u) {
      unsigned m = min(min(lsp[0], lsp[1]), min(lsp[2], lsp[3]));
      __hip_atomic_store(slots + bid, m, __ATOMIC_RELEASE,
                         __HIP_MEMORY_SCOPE_AGENT);
    }
    return;
  }

  float value = *valuep;
  float sv = value * 1.41421356237309515f;
  const float lo = __uint_as_float(0xBF7FFFFFu);  // nextafter(-1.f, 0.f)

  unsigned w = bid - PREPB;
  if (w < p2.nc_end) {
    // ---------- nonclass chunk: no dependency on prep ----------
    TP P = p0;
    if (w >= p0.nc_end) P = p1;
    if (w >= p1.nc_end) P = p2;
    unsigned local = w - P.nc_base;
    unsigned chunk = (local < P.lo_cnt) ? local : P.hi_start + (local - P.lo_cnt);
    process_chunk<false>(P, chunk << 10, tid, 0.0f, sv, lo);
    return;
  }

  // ---------- class chunk: wait for prep (validity spin), reduce min ------
  w -= p2.nc_end;
  TP P = p0;
  if (w >= p0.cls_end) P = p1;
  if (w >= p1.cls_end) P = p2;
  unsigned chunk = P.cls_lo + (w - P.cls_base);

  __shared__ unsigned ls[4];
  __shared__ int okf;
  float clsmin;
  for (;;) {
    if (tid == 0u) okf = 1;
    __syncthreads();
    unsigned u = 0x7FFFFFFFu;
    bool ok = true;
    if (tid < P.slot_cnt) {
      u = __hip_atomic_load(slots + P.slot_base + tid, __ATOMIC_ACQUIRE,
                            __HIP_MEMORY_SCOPE_AGENT);
      ok = ((u >> 31) == 0u) && (u != 0u);   // valid encoded negative min
    }
    if (!ok) okf = 0;                        // benign shared race (writes 0)
    unsigned r = u;
    for (int off = 32; off > 0; off >>= 1) {
      unsigned o = __shfl_down(r, (unsigned)off, 64);
      r = (o < r) ? o : r;
    }
    if ((tid & 63u) == 0u) ls[tid >> 6] = r;
    __syncthreads();
    if (okf) { clsmin = decf(min(min(ls[0], ls[1]), min(ls[2], ls[3]))); break; }
    __builtin_amdgcn_s_sleep(32);
  }

  process_chunk<true>(P, chunk << 10, tid, clsmin, sv, lo);
}

extern "C" void kernel_launch(void* const* d_in, const int* in_sizes, int n_in,
                              void* d_out, int out_size, void* d_ws, size_t ws_size,
                              hipStream_t stream) {
  const float* xs[3] = {(const float*)d_in[0], (const float*)d_in[1], (const float*)d_in[2]};
  const float* valuep = (const float*)d_in[3];
  float* out = (float*)d_out;

  const unsigned Ns[3] = {25600u, 6400u, 1600u};
  const unsigned ks[3] = {10u, 8u, 6u};   // N = 25 << k
  const unsigned slot_base[3] = {0u, 200u, 250u};
  const unsigned slot_cnt[3] = {200u, 50u, 13u};

  // workspace: midx0 | midx1 | midx2 | slots[263]
  int* midx[3];
  midx[0] = (int*)d_ws;
  midx[1] = midx[0] + Ns[0];
  midx[2] = midx[1] + Ns[1];
  unsigned* slots = (unsigned*)(midx[2] + Ns[2]);

  // Host-side key derivation (partitionable threefry):
  //   base = key(42) = (0,42); key_i = threefry(base,(0,i));
  //   split(key_i) -> k1 = threefry(key_i,(0,0)) [uniform], k2 = threefry(key_i,(0,1)) [normal]
  TP p[3];
  unsigned nc_acc = 0, cls_acc = 0;
  float* outp = out;
  for (int i = 0; i < 3; ++i) {
    uint32_t f0, f1;
    tf2x32(0u, 42u, 0u, (uint32_t)i, f0, f1);
    tf2x32(f0, f1, 0u, 0u, p[i].uk0, p[i].uk1);
    tf2x32(f0, f1, 0u, 1u, p[i].nk0, p[i].nk1);
    const unsigned N = Ns[i];
    p[i].x = xs[i];
    p[i].out = outp;
    p[i].midx = midx[i];
    p[i].k = ks[i];
    p[i].N = N;
    p[i].tot = 680u * N;
    const unsigned chunks = (p[i].tot + 1023u) / 1024u;
    const unsigned cls_lo = (5u * N) >> 10;              // first chunk w/ class
    const unsigned cls_hi = (85u * N - 1u) >> 10;        // last chunk w/ class
    p[i].cls_lo = cls_lo;
    p[i].lo_cnt = cls_lo;
    p[i].hi_start = cls_hi + 1u;
    const unsigned nc_cnt = cls_lo + (chunks - (cls_hi + 1u));
    const unsigned cls_cnt = cls_hi - cls_lo + 1u;
    p[i].nc_base = nc_acc;  nc_acc += nc_cnt;   p[i].nc_end = nc_acc;
    p[i].cls_base = cls_acc; cls_acc += cls_cnt; p[i].cls_end = cls_acc;
    p[i].slot_base = slot_base[i];
    p[i].slot_cnt = slot_cnt[i];
    outp += (size_t)680 * N;
  }

  mono<<<PREPB + nc_acc + cls_acc, 256, 0, stream>>>(p[0], p[1], p[2], slots, valuep);
}

// Round 12
// 65.685 us; speedup vs baseline: 1.8168x; 1.8168x over previous
//
#include <hip/hip_runtime.h>
#include <stdint.h>

// rotate-left via v_alignbit_b32 (1 instruction)
__device__ __forceinline__ uint32_t rotl(uint32_t v, int r) {
  return __builtin_amdgcn_alignbit(v, v, (uint32_t)(32 - r));
}

// ---------------- Threefry-2x32, 20 rounds (host key derivation) ----------
__host__ inline void tf2x32(uint32_t k0, uint32_t k1, uint32_t x0, uint32_t x1,
                            uint32_t& o0, uint32_t& o1) {
  uint32_t k2 = k0 ^ k1 ^ 0x1BD11BDAu;
#define TFR(r) { x0 += x1; x1 = (x1 << (r)) | (x1 >> (32 - (r))); x1 ^= x0; }
  x0 += k0; x1 += k1;
  TFR(13) TFR(15) TFR(26) TFR(6)  x0 += k1; x1 += k2 + 1u;
  TFR(17) TFR(29) TFR(16) TFR(24) x0 += k2; x1 += k0 + 2u;
  TFR(13) TFR(15) TFR(26) TFR(6)  x0 += k0; x1 += k1 + 3u;
  TFR(17) TFR(29) TFR(16) TFR(24) x0 += k1; x1 += k2 + 4u;
  TFR(13) TFR(15) TFR(26) TFR(6)  x0 += k2; x1 += k0 + 5u;
#undef TFR
  o0 = x0; o1 = x1;
}

// 4-chain lockstep threefry at counters (0, jb + STRIDE*i); out = o0^o1
// (JAX partitionable random_bits). Key injections fused into following
// round's add (v_add3), round-1 add merged into init.
template <unsigned STRIDE>
__device__ __forceinline__ void tf4(uint32_t k0, uint32_t k1, uint32_t jb,
                                    uint32_t out[4]) {
  uint32_t k2 = k0 ^ k1 ^ 0x1BD11BDAu;
  uint32_t k21 = k2 + 1u, k02 = k0 + 2u, k13 = k1 + 3u, k24 = k2 + 4u,
           k05 = k0 + 5u;
  uint32_t a[4], b[4];
  uint32_t jk = jb + k1;
#pragma unroll
  for (int i = 0; i < 4; ++i) {
    b[i] = jk + STRIDE * (unsigned)i;
    a[i] = k0 + b[i];                   // round-1 "a += b" merged with a = k0
  }
#pragma unroll
  for (int i = 0; i < 4; ++i) b[i] = rotl(b[i], 13) ^ a[i];  // round-1 tail
#define RND4(r)                                                        \
  _Pragma("unroll") for (int i = 0; i < 4; ++i) {                      \
    a[i] += b[i];                                                      \
    b[i] = rotl(b[i], (r)) ^ a[i];                                     \
  }
#define RNDI4(r, ka, kbn)                                              \
  _Pragma("unroll") for (int i = 0; i < 4; ++i) {                      \
    b[i] += (kbn);                                                     \
    a[i] = a[i] + (ka) + b[i];  /* v_add3_u32 */                       \
    b[i] = rotl(b[i], (r)) ^ a[i];                                     \
  }
  RND4(15) RND4(26) RND4(6)
  RNDI4(17, k1, k21) RND4(29) RND4(16) RND4(24)
  RNDI4(13, k2, k02) RND4(15) RND4(26) RND4(6)
  RNDI4(17, k0, k13) RND4(29) RND4(16) RND4(24)
  RNDI4(13, k1, k24) RND4(15) RND4(26) RND4(6)
#undef RND4
#undef RNDI4
#pragma unroll
  for (int i = 0; i < 4; ++i) out[i] = (a[i] + k2) ^ (b[i] + k05);
}

// order-preserving float<->uint encode for min on floats
__device__ __forceinline__ unsigned encf(float f) {
  unsigned u = __float_as_uint(f);
  return (u & 0x80000000u) ? ~u : (u | 0x80000000u);
}
__device__ __forceinline__ float decf(unsigned u) {
  unsigned b = (u & 0x80000000u) ? (u & 0x7FFFFFFFu) : ~u;
  return __uint_as_float(b);
}

struct TP {
  const float* x;
  float* out;
  int* midx;
  uint32_t uk0, uk1, nk0, nk1;
  unsigned k;         // N = 25 << k
  unsigned N;
  unsigned tot;       // 680 * N
  unsigned lo_cnt;    // nonclass chunks below class region
  unsigned hi_start;  // first chunk after class region
  unsigned nc_base, nc_end;    // prefix range of nonclass chunks (kernel A)
  unsigned cls_lo;             // first class-involved chunk
  unsigned cls_base, cls_end;  // prefix range of class chunks (kernel B)
  unsigned slot_base, slot_cnt;  // per-block min slots of this tensor
};

#define PREPB 263u

// process one 2048-elem chunk starting at element s of tensor P (8/thread).
// zlite: noise = sv*sqrt2*erfinv(u). 3-term Giles central poly re-fit in
// L = log2(1-x^2) and EXTRAPOLATED over the tail (w in [5,16]): max z-error
// 0.24 at w=16 (~1.5 samples expected) -> output error <= 0.017, budget 0.108.
// sv*sqrt2 folded into the poly coefficients (3 muls/thread).
template <bool CLS>
__device__ __forceinline__ void process_chunk(
    const TP& P, unsigned s, unsigned tid, float clsmin, float sv) {
  unsigned i0 = s + tid * 8u;
  if (i0 >= P.tot) return;
  bool h2 = (i0 + 4u) < P.tot;       // second float4 valid (only t2 tail chunk)

  unsigned bc = __umulhi(i0 >> P.k, 0x51EB851Fu) >> 3;  // (i0/2^k)/25
  unsigned n0 = i0 - bc * P.N;       // 8 consecutive n, same (b,c): N%8==0
  unsigned b = (bc * 772u) >> 16;    // exact for bc < 680
  unsigned c = bc - b * 85u;

  float4 va = *reinterpret_cast<const float4*>(P.x + i0);
  float4 vb = h2 ? *reinterpret_cast<const float4*>(P.x + i0 + 4) : va;

  // ---- noise bits: 8 threefry chains (two lockstep-4 groups) ----
  unsigned jb = (b * P.N + n0) * 85u + c;  // noise array [B,N,C] flat index
  uint32_t nb[8];
  tf4<85u>(P.nk0, P.nk1, jb, nb);
  tf4<85u>(P.nk0, P.nk1, jb + 340u, nb + 4);

  // sv-folded poly coefficients (per-thread, amortized over 8 elems)
  float A = -0.00200719f * sv, B = -0.18543758f * sv, C = 0.85869708f * sv;
  const float lo = __uint_as_float(0xBF7FFFFFu);  // nextafter(-1.f, 0.f)

  float x8[8], L8[8], p8[8];
#pragma unroll
  for (int q = 0; q < 8; ++q) {
    float f = __uint_as_float((nb[q] >> 9) | 0x3F800000u) - 1.0f;  // [0,1)
    x8[q] = fmaf(f, 2.0f, lo);                   // [lo, 1): no clamp needed
  }
#pragma unroll
  for (int q = 0; q < 8; ++q) L8[q] = __log2f(fmaf(-x8[q], x8[q], 1.0f));
#pragma unroll
  for (int q = 0; q < 8; ++q) p8[q] = fmaf(A, L8[q], B);
#pragma unroll
  for (int q = 0; q < 8; ++q) p8[q] = fmaf(p8[q], L8[q], C);

  float vv[8] = {va.x, va.y, va.z, va.w, vb.x, vb.y, vb.z, vb.w};

  if (CLS) {
    // ---- class scatter-replace (batch 0, channels 5..84) ----
    if (b == 0u && c >= 5u) {
      unsigned kk = c - 5u;
      int4 ma = *reinterpret_cast<const int4*>(P.midx + n0);
      int4 mb = *reinterpret_cast<const int4*>(P.midx + n0 + 4);  // class chunks never partial
      uint32_t ub[8];
      unsigned ju = n0 * 80u + kk;               // uniform array [N,80]
      tf4<80u>(P.uk0, P.uk1, ju, ub);
      tf4<80u>(P.uk0, P.uk1, ju + 320u, ub + 4);
      int mm[8] = {ma.x, ma.y, ma.z, ma.w, mb.x, mb.y, mb.z, mb.w};
      float ncm = -clsmin;
#pragma unroll
      for (int q = 0; q < 8; ++q) {
        if ((unsigned)mm[q] != kk) {
          float g = __uint_as_float((ub[q] >> 9) | 0x3F800000u);  // [1,2)
          vv[q] = fmaf(g, clsmin, ncm);          // (g-1)*clsmin
        }
      }
    }
  }

#pragma unroll
  for (int q = 0; q < 8; ++q) vv[q] = fmaf(p8[q], x8[q], vv[q]);
  *reinterpret_cast<float4*>(P.out + i0) = make_float4(vv[0], vv[1], vv[2], vv[3]);
  if (h2)
    *reinterpret_cast<float4*>(P.out + i0 + 4) = make_float4(vv[4], vv[5], vv[6], vv[7]);
}

// ---------------- kernel A: prep blocks + nonclass-chunk blocks ------------
// Blocks 0..262 compute argmax/min (write midx + slot[bid]; no reader in A).
// Blocks 263.. process chunks with NO batch-0 class elements.
__global__ __launch_bounds__(256) void kA(
    TP p0, TP p1, TP p2, unsigned* __restrict__ slots,
    const float* __restrict__ valuep) {
  const unsigned bid = blockIdx.x, tid = threadIdx.x;

  if (bid < PREPB) {
    // ---------- prep: per-pixel argmax + per-block min ----------
    const float* x; int* midx; unsigned N; unsigned lb;
    if (bid < 200u)      { x = p0.x; midx = p0.midx; N = 25600u; lb = bid; }
    else if (bid < 250u) { x = p1.x; midx = p1.midx; N = 6400u;  lb = bid - 200u; }
    else                 { x = p2.x; midx = p2.midx; N = 1600u;  lb = bid - 250u; }
    unsigned p = lb * 128u + (tid >> 1);
    unsigned h = tid & 1u;           // half: channels 40h .. 40h+39
    float best = -INFINITY, mn = INFINITY;
    int bi = 0;
    if (p < N) {
      const float* pp = x + (5u + 40u * h) * N + p;
#pragma unroll 8
      for (int k = 0; k < 40; ++k) {
        float v = pp[(unsigned)k * N];
        if (v > best) { best = v; bi = (int)(40u * h) + k; }  // '>': first max
        mn = fminf(mn, v);
      }
    }
    float ob = __shfl_xor(best, 1, 64);
    int obi = __shfl_xor(bi, 1, 64);
    float omn = __shfl_xor(mn, 1, 64);
    float bE = (h == 0u) ? best : ob;  int iE = (h == 0u) ? bi : obi;
    float bO = (h == 0u) ? ob : best;  int iO = (h == 0u) ? obi : bi;
    int mbi = (bO > bE) ? iO : iE;     // ties -> lower-k half (first max)
    mn = fminf(mn, omn);
    if (h == 0u && p < N) midx[p] = mbi;
    unsigned u = encf(mn);
    for (int off = 32; off > 0; off >>= 1) {
      unsigned o = __shfl_down(u, (unsigned)off, 64);
      u = (o < u) ? o : u;
    }
    __shared__ unsigned ls[4];
    if ((tid & 63u) == 0u) ls[tid >> 6] = u;
    __syncthreads();
    if (tid == 0u) {
      unsigned m = min(min(ls[0], ls[1]), min(ls[2], ls[3]));
      slots[bid] = m;   // plain store: kernel boundary orders it for kB
    }
    return;
  }

  unsigned w = bid - PREPB;
  TP P = p0;
  if (w >= p0.nc_end) P = p1;
  if (w >= p1.nc_end) P = p2;
  unsigned local = w - P.nc_base;
  unsigned chunk = (local < P.lo_cnt) ? local : P.hi_start + (local - P.lo_cnt);

  float sv = *valuep * 1.41421356237309515f;
  process_chunk<false>(P, chunk << 11, tid, 0.0f, sv);
}

// ---------------- kernel B: class-involved chunks (after prep) -------------
__global__ __launch_bounds__(256) void kB(
    TP p0, TP p1, TP p2, const unsigned* __restrict__ slots,
    const float* __restrict__ valuep) {
  const unsigned bid = blockIdx.x, tid = threadIdx.x;
  TP P = p0;
  if (bid >= p0.cls_end) P = p1;
  if (bid >= p1.cls_end) P = p2;
  unsigned chunk = P.cls_lo + (bid - P.cls_base);

  // reduce this tensor's per-block min slots (slot_cnt <= 200 < 256)
  __shared__ unsigned ls[4];
  unsigned u = (tid < P.slot_cnt) ? slots[P.slot_base + tid] : 0xFFFFFFFFu;
  for (int off = 32; off > 0; off >>= 1) {
    unsigned o = __shfl_down(u, (unsigned)off, 64);
    u = (o < u) ? o : u;
  }
  if ((tid & 63u) == 0u) ls[tid >> 6] = u;
  __syncthreads();
  float clsmin = decf(min(min(ls[0], ls[1]), min(ls[2], ls[3])));

  float sv = *valuep * 1.41421356237309515f;
  process_chunk<true>(P, chunk << 11, tid, clsmin, sv);
}

extern "C" void kernel_launch(void* const* d_in, const int* in_sizes, int n_in,
                              void* d_out, int out_size, void* d_ws, size_t ws_size,
                              hipStream_t stream) {
  const float* xs[3] = {(const float*)d_in[0], (const float*)d_in[1], (const float*)d_in[2]};
  const float* valuep = (const float*)d_in[3];
  float* out = (float*)d_out;

  const unsigned Ns[3] = {25600u, 6400u, 1600u};
  const unsigned ks[3] = {10u, 8u, 6u};   // N = 25 << k
  const unsigned slot_base[3] = {0u, 200u, 250u};
  const unsigned slot_cnt[3] = {200u, 50u, 13u};

  // workspace: midx0 | midx1 | midx2 | slots[263]
  int* midx[3];
  midx[0] = (int*)d_ws;
  midx[1] = midx[0] + Ns[0];
  midx[2] = midx[1] + Ns[1];
  unsigned* slots = (unsigned*)(midx[2] + Ns[2]);

  // Host-side key derivation (partitionable threefry):
  //   base = key(42) = (0,42); key_i = threefry(base,(0,i));
  //   split(key_i) -> k1 = threefry(key_i,(0,0)) [uniform], k2 = threefry(key_i,(0,1)) [normal]
  TP p[3];
  unsigned nc_acc = 0, cls_acc = 0;
  float* outp = out;
  for (int i = 0; i < 3; ++i) {
    uint32_t f0, f1;
    tf2x32(0u, 42u, 0u, (uint32_t)i, f0, f1);
    tf2x32(f0, f1, 0u, 0u, p[i].uk0, p[i].uk1);
    tf2x32(f0, f1, 0u, 1u, p[i].nk0, p[i].nk1);
    const unsigned N = Ns[i];
    p[i].x = xs[i];
    p[i].out = outp;
    p[i].midx = midx[i];
    p[i].k = ks[i];
    p[i].N = N;
    p[i].tot = 680u * N;
    const unsigned chunks = (p[i].tot + 2047u) / 2048u;
    const unsigned cls_lo = (5u * N) >> 11;              // first chunk w/ class
    const unsigned cls_hi = (85u * N - 1u) >> 11;        // last chunk w/ class
    p[i].cls_lo = cls_lo;
    p[i].lo_cnt = cls_lo;
    p[i].hi_start = cls_hi + 1u;
    const unsigned nc_cnt = cls_lo + (chunks - (cls_hi + 1u));
    const unsigned cls_cnt = cls_hi - cls_lo + 1u;
    p[i].nc_base = nc_acc;  nc_acc += nc_cnt;   p[i].nc_end = nc_acc;
    p[i].cls_base = cls_acc; cls_acc += cls_cnt; p[i].cls_end = cls_acc;
    p[i].slot_base = slot_base[i];
    p[i].slot_cnt = slot_cnt[i];
    outp += (size_t)680 * N;
  }

  kA<<<PREPB + nc_acc, 256, 0, stream>>>(p[0], p[1], p[2], slots, valuep);
  kB<<<cls_acc, 256, 0, stream>>>(p[0], p[1], p[2], slots, valuep);
}

// Round 13
// 62.760 us; speedup vs baseline: 1.9015x; 1.0466x over previous
//
#include <hip/hip_runtime.h>
#include <stdint.h>

// rotate-left via v_alignbit_b32 (1 instruction)
__device__ __forceinline__ uint32_t rotl(uint32_t v, int r) {
  return __builtin_amdgcn_alignbit(v, v, (uint32_t)(32 - r));
}

// ---------------- Threefry-2x32, 20 rounds (host key derivation) ----------
__host__ inline void tf2x32(uint32_t k0, uint32_t k1, uint32_t x0, uint32_t x1,
                            uint32_t& o0, uint32_t& o1) {
  uint32_t k2 = k0 ^ k1 ^ 0x1BD11BDAu;
#define TFR(r) { x0 += x1; x1 = (x1 << (r)) | (x1 >> (32 - (r))); x1 ^= x0; }
  x0 += k0; x1 += k1;
  TFR(13) TFR(15) TFR(26) TFR(6)  x0 += k1; x1 += k2 + 1u;
  TFR(17) TFR(29) TFR(16) TFR(24) x0 += k2; x1 += k0 + 2u;
  TFR(13) TFR(15) TFR(26) TFR(6)  x0 += k0; x1 += k1 + 3u;
  TFR(17) TFR(29) TFR(16) TFR(24) x0 += k1; x1 += k2 + 4u;
  TFR(13) TFR(15) TFR(26) TFR(6)  x0 += k2; x1 += k0 + 5u;
#undef TFR
  o0 = x0; o1 = x1;
}

// 4-chain lockstep threefry at counters (0, jb + STRIDE*i); out = o0^o1
// (JAX partitionable random_bits). Key injections fused into following
// round's add (v_add3), round-1 add merged into init.
template <unsigned STRIDE>
__device__ __forceinline__ void tf4(uint32_t k0, uint32_t k1, uint32_t jb,
                                    uint32_t out[4]) {
  uint32_t k2 = k0 ^ k1 ^ 0x1BD11BDAu;
  uint32_t k21 = k2 + 1u, k02 = k0 + 2u, k13 = k1 + 3u, k24 = k2 + 4u,
           k05 = k0 + 5u;
  uint32_t a[4], b[4];
  uint32_t jk = jb + k1;
#pragma unroll
  for (int i = 0; i < 4; ++i) {
    b[i] = jk + STRIDE * (unsigned)i;
    a[i] = k0 + b[i];                   // round-1 "a += b" merged with a = k0
  }
#pragma unroll
  for (int i = 0; i < 4; ++i) b[i] = rotl(b[i], 13) ^ a[i];  // round-1 tail
#define RND4(r)                                                        \
  _Pragma("unroll") for (int i = 0; i < 4; ++i) {                      \
    a[i] += b[i];                                                      \
    b[i] = rotl(b[i], (r)) ^ a[i];                                     \
  }
#define RNDI4(r, ka, kbn)                                              \
  _Pragma("unroll") for (int i = 0; i < 4; ++i) {                      \
    b[i] += (kbn);                                                     \
    a[i] = a[i] + (ka) + b[i];  /* v_add3_u32 */                       \
    b[i] = rotl(b[i], (r)) ^ a[i];                                     \
  }
  RND4(15) RND4(26) RND4(6)
  RNDI4(17, k1, k21) RND4(29) RND4(16) RND4(24)
  RNDI4(13, k2, k02) RND4(15) RND4(26) RND4(6)
  RNDI4(17, k0, k13) RND4(29) RND4(16) RND4(24)
  RNDI4(13, k1, k24) RND4(15) RND4(26) RND4(6)
#undef RND4
#undef RNDI4
#pragma unroll
  for (int i = 0; i < 4; ++i) out[i] = (a[i] + k2) ^ (b[i] + k05);
}

// order-preserving float<->uint encode for min on floats
__device__ __forceinline__ unsigned encf(float f) {
  unsigned u = __float_as_uint(f);
  return (u & 0x80000000u) ? ~u : (u | 0x80000000u);
}
__device__ __forceinline__ float decf(unsigned u) {
  unsigned b = (u & 0x80000000u) ? (u & 0x7FFFFFFFu) : ~u;
  return __uint_as_float(b);
}

struct TP {
  const float* x;
  float* out;
  int* midx;
  uint32_t uk0, uk1, nk0, nk1;
  unsigned k;         // N = 25 << k
  unsigned N;
  unsigned tot;       // 680 * N
  unsigned lo_cnt;    // nonclass chunks below class region
  unsigned hi_start;  // first chunk after class region
  unsigned nc_base, nc_end;    // prefix range of nonclass chunks (kernel A)
  unsigned cls_lo;             // first class-involved chunk
  unsigned cls_base, cls_end;  // prefix range of class chunks (kernel B)
  unsigned slot_base, slot_cnt;  // per-block min slots of this tensor
};

#define PREPB 263u

// process one 1024-elem chunk starting at element s of tensor P (4/thread).
// zlite: noise = value*sqrt2*erfinv(u), 3-term poly fit in L = log2(1-x^2),
// extrapolated over the tail (w in [5,16]): z-err <= 0.24 at w=16 (~1.5
// samples expected chip-wide) -> output err <= 0.017, budget 0.108.
// value*sqrt2 folded into the coefficients (3 muls/thread, amortized).
template <bool CLS>
__device__ __forceinline__ void process_chunk(
    const TP& P, unsigned s, unsigned tid, float clsmin, float sv) {
  unsigned i0 = s + tid * 4u;
  if (i0 >= P.tot) return;

  unsigned bc = __umulhi(i0 >> P.k, 0x51EB851Fu) >> 3;  // (i0/2^k)/25
  unsigned n0 = i0 - bc * P.N;       // 4 consecutive n, same (b,c)
  unsigned b = (bc * 772u) >> 16;    // exact for bc < 680
  unsigned c = bc - b * 85u;

  float4 va = *reinterpret_cast<const float4*>(P.x + i0);

  // ---- noise bits: 4 lockstep threefry chains ----
  unsigned jb = (b * P.N + n0) * 85u + c;  // noise array [B,N,C] flat index
  uint32_t nb[4];
  tf4<85u>(P.nk0, P.nk1, jb, nb);

  // sv-folded poly coefficients
  float A = -0.00200719f * sv, B = -0.18543758f * sv, C = 0.85869708f * sv;
  const float lo = __uint_as_float(0xBF7FFFFFu);  // nextafter(-1.f, 0.f)

  float x4[4], L4[4], p4[4];
#pragma unroll
  for (int q = 0; q < 4; ++q) {
    float f = __uint_as_float((nb[q] >> 9) | 0x3F800000u) - 1.0f;  // [0,1)
    x4[q] = fmaf(f, 2.0f, lo);                   // [lo, 1): no clamp needed
  }
#pragma unroll
  for (int q = 0; q < 4; ++q) L4[q] = __log2f(fmaf(-x4[q], x4[q], 1.0f));
#pragma unroll
  for (int q = 0; q < 4; ++q) p4[q] = fmaf(A, L4[q], B);
#pragma unroll
  for (int q = 0; q < 4; ++q) p4[q] = fmaf(p4[q], L4[q], C);

  float vv[4] = {va.x, va.y, va.z, va.w};

  if (CLS) {
    // ---- class scatter-replace (batch 0, channels 5..84) ----
    if (b == 0u && c >= 5u) {
      unsigned kk = c - 5u;
      int4 ma = *reinterpret_cast<const int4*>(P.midx + n0);
      uint32_t ub[4];
      tf4<80u>(P.uk0, P.uk1, n0 * 80u + kk, ub);   // uniform array [N,80]
      int mm[4] = {ma.x, ma.y, ma.z, ma.w};
      float ncm = -clsmin;
#pragma unroll
      for (int q = 0; q < 4; ++q) {
        if ((unsigned)mm[q] != kk) {
          float g = __uint_as_float((ub[q] >> 9) | 0x3F800000u);  // [1,2)
          vv[q] = fmaf(g, clsmin, ncm);            // (g-1)*clsmin
        }
      }
    }
  }

#pragma unroll
  for (int q = 0; q < 4; ++q) vv[q] = fmaf(p4[q], x4[q], vv[q]);
  *reinterpret_cast<float4*>(P.out + i0) = make_float4(vv[0], vv[1], vv[2], vv[3]);
}

// ---------------- kernel A: prep blocks + nonclass-chunk blocks ------------
// Blocks 0..262 compute argmax/min (write midx + slot[bid]; no reader in A).
// Blocks 263.. process chunks with NO batch-0 class elements.
__global__ __launch_bounds__(256) void kA(
    TP p0, TP p1, TP p2, unsigned* __restrict__ slots,
    const float* __restrict__ valuep) {
  const unsigned bid = blockIdx.x, tid = threadIdx.x;

  if (bid < PREPB) {
    // ---------- prep: per-pixel argmax + per-block min ----------
    const float* x; int* midx; unsigned N; unsigned lb;
    if (bid < 200u)      { x = p0.x; midx = p0.midx; N = 25600u; lb = bid; }
    else if (bid < 250u) { x = p1.x; midx = p1.midx; N = 6400u;  lb = bid - 200u; }
    else                 { x = p2.x; midx = p2.midx; N = 1600u;  lb = bid - 250u; }
    unsigned p = lb * 128u + (tid >> 1);
    unsigned h = tid & 1u;           // half: channels 40h .. 40h+39
    float best = -INFINITY, mn = INFINITY;
    int bi = 0;
    if (p < N) {
      const float* pp = x + (5u + 40u * h) * N + p;
#pragma unroll 8
      for (int k = 0; k < 40; ++k) {
        float v = pp[(unsigned)k * N];
        if (v > best) { best = v; bi = (int)(40u * h) + k; }  // '>': first max
        mn = fminf(mn, v);
      }
    }
    float ob = __shfl_xor(best, 1, 64);
    int obi = __shfl_xor(bi, 1, 64);
    float omn = __shfl_xor(mn, 1, 64);
    float bE = (h == 0u) ? best : ob;  int iE = (h == 0u) ? bi : obi;
    float bO = (h == 0u) ? ob : best;  int iO = (h == 0u) ? obi : bi;
    int mbi = (bO > bE) ? iO : iE;     // ties -> lower-k half (first max)
    mn = fminf(mn, omn);
    if (h == 0u && p < N) midx[p] = mbi;
    unsigned u = encf(mn);
    for (int off = 32; off > 0; off >>= 1) {
      unsigned o = __shfl_down(u, (unsigned)off, 64);
      u = (o < u) ? o : u;
    }
    __shared__ unsigned ls[4];
    if ((tid & 63u) == 0u) ls[tid >> 6] = u;
    __syncthreads();
    if (tid == 0u) {
      unsigned m = min(min(ls[0], ls[1]), min(ls[2], ls[3]));
      slots[bid] = m;   // plain store: kernel boundary orders it for kB
    }
    return;
  }

  unsigned w = bid - PREPB;
  TP P = p0;
  if (w >= p0.nc_end) P = p1;
  if (w >= p1.nc_end) P = p2;
  unsigned local = w - P.nc_base;
  unsigned chunk = (local < P.lo_cnt) ? local : P.hi_start + (local - P.lo_cnt);

  float sv = *valuep * 1.41421356237309515f;
  process_chunk<false>(P, chunk << 10, tid, 0.0f, sv);
}

// ---------------- kernel B: class-involved chunks (after prep) -------------
__global__ __launch_bounds__(256) void kB(
    TP p0, TP p1, TP p2, const unsigned* __restrict__ slots,
    const float* __restrict__ valuep) {
  const unsigned bid = blockIdx.x, tid = threadIdx.x;
  TP P = p0;
  if (bid >= p0.cls_end) P = p1;
  if (bid >= p1.cls_end) P = p2;
  unsigned chunk = P.cls_lo + (bid - P.cls_base);

  // reduce this tensor's per-block min slots (slot_cnt <= 200 < 256)
  __shared__ unsigned ls[4];
  unsigned u = (tid < P.slot_cnt) ? slots[P.slot_base + tid] : 0xFFFFFFFFu;
  for (int off = 32; off > 0; off >>= 1) {
    unsigned o = __shfl_down(u, (unsigned)off, 64);
    u = (o < u) ? o : u;
  }
  if ((tid & 63u) == 0u) ls[tid >> 6] = u;
  __syncthreads();
  float clsmin = decf(min(min(ls[0], ls[1]), min(ls[2], ls[3])));

  float sv = *valuep * 1.41421356237309515f;
  process_chunk<true>(P, chunk << 10, tid, clsmin, sv);
}

extern "C" void kernel_launch(void* const* d_in, const int* in_sizes, int n_in,
                              void* d_out, int out_size, void* d_ws, size_t ws_size,
                              hipStream_t stream) {
  const float* xs[3] = {(const float*)d_in[0], (const float*)d_in[1], (const float*)d_in[2]};
  const float* valuep = (const float*)d_in[3];
  float* out = (float*)d_out;

  const unsigned Ns[3] = {25600u, 6400u, 1600u};
  const unsigned ks[3] = {10u, 8u, 6u};   // N = 25 << k
  const unsigned slot_base[3] = {0u, 200u, 250u};
  const unsigned slot_cnt[3] = {200u, 50u, 13u};

  // workspace: midx0 | midx1 | midx2 | slots[263]
  int* midx[3];
  midx[0] = (int*)d_ws;
  midx[1] = midx[0] + Ns[0];
  midx[2] = midx[1] + Ns[1];
  unsigned* slots = (unsigned*)(midx[2] + Ns[2]);

  // Host-side key derivation (partitionable threefry):
  //   base = key(42) = (0,42); key_i = threefry(base,(0,i));
  //   split(key_i) -> k1 = threefry(key_i,(0,0)) [uniform], k2 = threefry(key_i,(0,1)) [normal]
  TP p[3];
  unsigned nc_acc = 0, cls_acc = 0;
  float* outp = out;
  for (int i = 0; i < 3; ++i) {
    uint32_t f0, f1;
    tf2x32(0u, 42u, 0u, (uint32_t)i, f0, f1);
    tf2x32(f0, f1, 0u, 0u, p[i].uk0, p[i].uk1);
    tf2x32(f0, f1, 0u, 1u, p[i].nk0, p[i].nk1);
    const unsigned N = Ns[i];
    p[i].x = xs[i];
    p[i].out = outp;
    p[i].midx = midx[i];
    p[i].k = ks[i];
    p[i].N = N;
    p[i].tot = 680u * N;
    const unsigned chunks = (p[i].tot + 1023u) / 1024u;
    const unsigned cls_lo = (5u * N) >> 10;              // first chunk w/ class
    const unsigned cls_hi = (85u * N - 1u) >> 10;        // last chunk w/ class
    p[i].cls_lo = cls_lo;
    p[i].lo_cnt = cls_lo;
    p[i].hi_start = cls_hi + 1u;
    const unsigned nc_cnt = cls_lo + (chunks - (cls_hi + 1u));
    const unsigned cls_cnt = cls_hi - cls_lo + 1u;
    p[i].nc_base = nc_acc;  nc_acc += nc_cnt;   p[i].nc_end = nc_acc;
    p[i].cls_base = cls_acc; cls_acc += cls_cnt; p[i].cls_end = cls_acc;
    p[i].slot_base = slot_base[i];
    p[i].slot_cnt = slot_cnt[i];
    outp += (size_t)680 * N;
  }

  kA<<<PREPB + nc_acc, 256, 0, stream>>>(p[0], p[1], p[2], slots, valuep);
  kB<<<cls_acc, 256, 0, stream>>>(p[0], p[1], p[2], slots, valuep);
}